// Round 5
// baseline (814.492 us; speedup 1.0000x reference)
//
#include <hip/hip_runtime.h>

#define N_NODES 100000
#define N_EDGES 1600000
#define D 64
#define BROWS 128                              // rows per bucket
#define NB 782                                 // (100000+127)/128
#define PBLK 512                               // partition blocks
#define CHUNK ((N_EDGES + PBLK - 1) / PBLK)    // 3125
#define FLATN (NB * PBLK)                      // 400384
#define SB1 ((FLATN + 255) / 256)              // 1564 (<=2048 for scan2)
#define SLICE_F 16                             // features per slice (3.2 MB bf16 slice fits 4MB XCD L2)

__device__ __forceinline__ unsigned short f2b(float f) {
    unsigned u = __float_as_uint(f);
    u += 0x7FFF + ((u >> 16) & 1);             // round-to-nearest-even
    return (unsigned short)(u >> 16);
}
__device__ __forceinline__ float b2f(unsigned short v) {
    return __uint_as_float(((unsigned)v) << 16);
}

// ---- pass 1: per-(block,bucket) edge counts via LDS histogram ----
__global__ void count_kernel(const int* __restrict__ ei, int* __restrict__ counts) {
    __shared__ int h[NB];
    for (int i = threadIdx.x; i < NB; i += 256) h[i] = 0;
    __syncthreads();
    int s = blockIdx.x * CHUNK;
    int e = min(s + CHUNK, N_EDGES);
    for (int i = s + (int)threadIdx.x; i < e; i += 256) {
        int r = ei[i], c = ei[N_EDGES + i];
        if (r != c) atomicAdd(&h[r >> 7], 1);
    }
    __syncthreads();
    for (int i = threadIdx.x; i < NB; i += 256) counts[i * PBLK + blockIdx.x] = h[i];
}

// ---- pass 2a: per-block exclusive scan (in place) ----
__global__ void scan1_kernel(int* __restrict__ a, int* __restrict__ blocksums) {
    __shared__ int s[256];
    int i = blockIdx.x * 256 + threadIdx.x;
    int v = (i < FLATN) ? a[i] : 0;
    s[threadIdx.x] = v;
    __syncthreads();
    for (int off = 1; off < 256; off <<= 1) {
        int t = (threadIdx.x >= off) ? s[threadIdx.x - off] : 0;
        __syncthreads();
        s[threadIdx.x] += t;
        __syncthreads();
    }
    if (i < FLATN) a[i] = s[threadIdx.x] - v;
    if (threadIdx.x == 255) blocksums[blockIdx.x] = s[255];
}

// ---- pass 2b: scan SB1 block sums, 2 per thread (SB1 <= 2048) ----
__global__ void scan2_kernel(int* __restrict__ blocksums, int* __restrict__ totalptr) {
    __shared__ int s[1024];
    int t = threadIdx.x;
    int i0 = 2 * t, i1 = 2 * t + 1;
    int a0 = (i0 < SB1) ? blocksums[i0] : 0;
    int a1 = (i1 < SB1) ? blocksums[i1] : 0;
    s[t] = a0 + a1;
    __syncthreads();
    for (int off = 1; off < 1024; off <<= 1) {
        int u = (t >= off) ? s[t - off] : 0;
        __syncthreads();
        s[t] += u;
        __syncthreads();
    }
    int excl = s[t] - (a0 + a1);
    if (i0 < SB1) blocksums[i0] = excl;
    if (i1 < SB1) blocksums[i1] = excl + a0;
    if (t == 1023) totalptr[0] = s[1023];      // total non-self edges
}

// ---- pass 2c: add back block offsets ----
__global__ void scan3_kernel(int* __restrict__ a, const int* __restrict__ blocksums) {
    int i = blockIdx.x * blockDim.x + threadIdx.x;
    if (i < FLATN) a[i] += blocksums[i >> 8];
}

// ---- pass 3: partition scatter into per-(block,bucket) contiguous runs ----
__global__ void scatter_part_kernel(const int* __restrict__ ei, const int* __restrict__ offsets,
                                    int* __restrict__ epack) {
    __shared__ int cur[NB];
    for (int i = threadIdx.x; i < NB; i += 256) cur[i] = offsets[i * PBLK + blockIdx.x];
    __syncthreads();
    int s = blockIdx.x * CHUNK;
    int e = min(s + CHUNK, N_EDGES);
    for (int i = s + (int)threadIdx.x; i < e; i += 256) {
        int r = ei[i], c = ei[N_EDGES + i];
        if (r != c) {
            int p = atomicAdd(&cur[r >> 7], 1);
            epack[p] = ((r & 127) << 17) | c;   // c < 2^17, rlow 7 bits
        }
    }
}

// ---- pass 4: per-bucket degree histogram -> dinv ----
__global__ void deg_kernel(const int* __restrict__ offsets, const int* __restrict__ totalptr,
                           const int* __restrict__ epack, float* __restrict__ dinv) {
    __shared__ int h[BROWS];
    int b = blockIdx.x;
    int t = threadIdx.x;
    if (t < BROWS) h[t] = 0;
    int base = offsets[b * PBLK];
    int end = (b + 1 < NB) ? offsets[(b + 1) * PBLK] : totalptr[0];
    __syncthreads();
    for (int i = base + t; i < end; i += 256)
        atomicAdd(&h[__builtin_nontemporal_load(&epack[i]) >> 17], 1);
    __syncthreads();
    int row = b * BROWS + t;
    if (t < BROWS && row < N_NODES) dinv[row] = rsqrtf((float)(1 + h[t]));
}

// ---- pass 5: xs[d>>4][n][d&15] = bf16(x[n][d] * dinv[n]) ----
__global__ void convert_kernel(const float* __restrict__ x, const float* __restrict__ dinv,
                               unsigned short* __restrict__ xs) {
    int i = blockIdx.x * blockDim.x + threadIdx.x;   // over N*D/4
    if (i >= N_NODES * D / 4) return;
    float4 v = ((const float4*)x)[i];
    int n = i >> 4;                 // node
    int p = (i >> 2) & 3;           // slice
    int dl = (i & 3) * 4;           // feature offset within slice
    float di = dinv[n];
    ushort4 o;
    o.x = f2b(v.x * di);
    o.y = f2b(v.y * di);
    o.z = f2b(v.z * di);
    o.w = f2b(v.w * di);
    *(ushort4*)&xs[p * (N_NODES * SLICE_F) + n * SLICE_F + dl] = o;
}

// ---- pass 6 (x4): per-bucket LDS-accumulated gather over one 16-feature slice ----
__global__ void gather_pass_kernel(const unsigned short* __restrict__ xs_p,
                                   const float* __restrict__ dinv,
                                   const int* __restrict__ offsets,
                                   const int* __restrict__ totalptr,
                                   const int* __restrict__ epack,
                                   float* __restrict__ out, int dbase) {
    __shared__ float acc[BROWS * SLICE_F];
    int b = blockIdx.x;
    int t = threadIdx.x;
    for (int i = t; i < BROWS * SLICE_F; i += 256) acc[i] = 0.f;
    int base = offsets[b * PBLK];
    int end = (b + 1 < NB) ? offsets[(b + 1) * PBLK] : totalptr[0];
    __syncthreads();
    int grp = t >> 4, d = t & 15;
    for (int e = base + grp; e < end; e += 16) {
        int p = __builtin_nontemporal_load(&epack[e]);  // 16 lanes same addr -> HW broadcast
        int c = p & 0x1FFFF;
        int r = p >> 17;
        float v = b2f(xs_p[c * SLICE_F + d]);           // L2-resident slice
        atomicAdd(&acc[r * SLICE_F + d], v);
    }
    __syncthreads();
    int row0 = b * BROWS;
    for (int k = 0; k < 8; k++) {
        int rl = (t >> 4) + k * 16;
        int row = row0 + rl;
        if (row < N_NODES) {
            float self = b2f(xs_p[row * SLICE_F + d]);  // self-loop term (has dinv[row] already)
            float val = dinv[row] * (acc[rl * SLICE_F + d] + self);
            __builtin_nontemporal_store(val, &out[row * D + dbase + d]);
        }
    }
}

extern "C" void kernel_launch(void* const* d_in, const int* in_sizes, int n_in,
                              void* d_out, int out_size, void* d_ws, size_t ws_size,
                              hipStream_t stream) {
    const float* x = (const float*)d_in[0];
    const int* ei = (const int*)d_in[1];
    float* out = (float*)d_out;

    // workspace (~21.2 MB)
    int* offsets = (int*)d_ws;                          // [FLATN]
    int* blocksums = offsets + FLATN;                   // [2048]
    int* totalptr = blocksums + 2048;                   // [4]
    float* dinv = (float*)(totalptr + 4);               // [N_NODES]
    int* epack = (int*)(dinv + N_NODES);                // [N_EDGES]
    unsigned short* xs = (unsigned short*)(epack + N_EDGES); // [N_NODES*D] as [4][N][16]

    count_kernel<<<PBLK, 256, 0, stream>>>(ei, offsets);
    scan1_kernel<<<SB1, 256, 0, stream>>>(offsets, blocksums);
    scan2_kernel<<<1, 1024, 0, stream>>>(blocksums, totalptr);
    scan3_kernel<<<(FLATN + 255) / 256, 256, 0, stream>>>(offsets, blocksums);
    scatter_part_kernel<<<PBLK, 256, 0, stream>>>(ei, offsets, epack);
    deg_kernel<<<NB, 256, 0, stream>>>(offsets, totalptr, epack, dinv);
    convert_kernel<<<(N_NODES * D / 4 + 255) / 256, 256, 0, stream>>>(x, dinv, xs);
    for (int p = 0; p < 4; p++)
        gather_pass_kernel<<<NB, 256, 0, stream>>>(xs + p * (N_NODES * SLICE_F), dinv,
                                                   offsets, totalptr, epack, out, p * SLICE_F);
}

// Round 6
// 178.208 us; speedup vs baseline: 4.5705x; 4.5705x over previous
//
#include <hip/hip_runtime.h>

#define N_NODES 100000
#define N_EDGES 1600000
#define D 64
#define NB 391            // row buckets of 256 rows
#define PBLK 512          // partition blocks
#define CHUNK ((N_EDGES + PBLK - 1) / PBLK)   // 3125 edges per partition block
#define FLATN (NB * PBLK) // 200192 count-matrix entries
#define SB1 ((FLATN + 255) / 256)             // 782 scan blocks (<1024)

__device__ __forceinline__ unsigned short f2b(float f) {
    unsigned u = __float_as_uint(f);
    u += 0x7FFF + ((u >> 16) & 1);            // round-to-nearest-even
    return (unsigned short)(u >> 16);
}
__device__ __forceinline__ float b2f(unsigned short v) {
    return __uint_as_float(((unsigned)v) << 16);
}

// ---- pass 1: per-(block,bucket) edge counts via LDS histogram ----
__global__ void count_kernel(const int* __restrict__ ei, int* __restrict__ counts) {
    __shared__ int h[NB];
    for (int i = threadIdx.x; i < NB; i += 256) h[i] = 0;
    __syncthreads();
    int s = blockIdx.x * CHUNK;
    int e = min(s + CHUNK, N_EDGES);
    for (int i = s + (int)threadIdx.x; i < e; i += 256) {
        int r = ei[i], c = ei[N_EDGES + i];
        if (r != c) atomicAdd(&h[r >> 8], 1);
    }
    __syncthreads();
    for (int i = threadIdx.x; i < NB; i += 256) counts[i * PBLK + blockIdx.x] = h[i];
}

// ---- pass 2a: per-block exclusive scan (in place) ----
__global__ void scan1_kernel(int* __restrict__ a, int* __restrict__ blocksums) {
    __shared__ int s[256];
    int i = blockIdx.x * 256 + threadIdx.x;
    int v = (i < FLATN) ? a[i] : 0;
    s[threadIdx.x] = v;
    __syncthreads();
    for (int off = 1; off < 256; off <<= 1) {
        int t = (threadIdx.x >= off) ? s[threadIdx.x - off] : 0;
        __syncthreads();
        s[threadIdx.x] += t;
        __syncthreads();
    }
    if (i < FLATN) a[i] = s[threadIdx.x] - v;
    if (threadIdx.x == 255) blocksums[blockIdx.x] = s[255];
}

// ---- pass 2b: scan block sums (SB1=782 <= 1024); total -> rowptr[N_NODES] ----
__global__ void scan2_kernel(int* __restrict__ blocksums, int* __restrict__ rowptr) {
    __shared__ int s[1024];
    int t = threadIdx.x;
    int v = (t < SB1) ? blocksums[t] : 0;
    s[t] = v;
    __syncthreads();
    for (int off = 1; off < 1024; off <<= 1) {
        int u = (t >= off) ? s[t - off] : 0;
        __syncthreads();
        s[t] += u;
        __syncthreads();
    }
    if (t < SB1) blocksums[t] = s[t] - v;
    if (t == SB1 - 1) rowptr[N_NODES] = s[t];  // total non-self edges
}

// ---- pass 3: partition scatter into per-(block,bucket) contiguous runs.
//      (blocksums added inline; scan3 deleted) ----
__global__ void scatter_part_kernel(const int* __restrict__ ei, const int* __restrict__ offsets,
                                    const int* __restrict__ blocksums, int* __restrict__ epack) {
    __shared__ int cur[NB];
    for (int i = threadIdx.x; i < NB; i += 256) {
        int f = i * PBLK + blockIdx.x;
        cur[i] = offsets[f] + blocksums[f >> 8];
    }
    __syncthreads();
    int s = blockIdx.x * CHUNK;
    int e = min(s + CHUNK, N_EDGES);
    for (int i = s + (int)threadIdx.x; i < e; i += 256) {
        int r = ei[i], c = ei[N_EDGES + i];
        if (r != c) {
            int p = atomicAdd(&cur[r >> 8], 1);
            epack[p] = ((r & 255) << 17) | c;   // c < 2^17
        }
    }
}

// ---- pass 4: per-bucket LDS counting sort by row; emit rowptr, dinv, sortedCol ----
__global__ void rowsort_kernel(const int* __restrict__ offsets, const int* __restrict__ blocksums,
                               const int* __restrict__ total_src,
                               const int* __restrict__ epack, int* __restrict__ rowptr,
                               float* __restrict__ dinv, int* __restrict__ sortedCol) {
    __shared__ int h[256];
    __shared__ int sc[256];
    __shared__ int cur[256];
    int b = blockIdx.x;
    int t = threadIdx.x;
    int f0 = b * PBLK;
    int base = offsets[f0] + blocksums[f0 >> 8];
    int end;
    if (b + 1 < NB) {
        int f1 = (b + 1) * PBLK;
        end = offsets[f1] + blocksums[f1 >> 8];
    } else {
        end = total_src[N_NODES];
    }
    h[t] = 0;
    __syncthreads();
    for (int i = base + t; i < end; i += 256) atomicAdd(&h[epack[i] >> 17], 1);
    __syncthreads();
    int v = h[t];
    sc[t] = v;
    __syncthreads();
    for (int off = 1; off < 256; off <<= 1) {
        int u = (t >= off) ? sc[t - off] : 0;
        __syncthreads();
        sc[t] += u;
        __syncthreads();
    }
    int excl = sc[t] - v;
    int row = b * 256 + t;
    if (row < N_NODES) {
        rowptr[row] = base + excl;
        dinv[row] = rsqrtf((float)(1 + v));
    }
    cur[t] = base + excl;
    __syncthreads();
    for (int i = base + t; i < end; i += 256) {
        int p = epack[i];
        int pos = atomicAdd(&cur[p >> 17], 1);
        sortedCol[pos] = p & 0x1FFFF;
    }
}

// ---- pass 5: xs[i][d] = bf16(x[i][d] * dinv[i]) ----
__global__ void convert_kernel(const float* __restrict__ x, const float* __restrict__ dinv,
                               unsigned short* __restrict__ xs) {
    int i = blockIdx.x * blockDim.x + threadIdx.x;   // over N*D/4
    if (i >= N_NODES * D / 4) return;
    float4 v = ((const float4*)x)[i];
    float di = dinv[(i * 4) >> 6];
    ushort4 o;
    o.x = f2b(v.x * di);
    o.y = f2b(v.y * di);
    o.z = f2b(v.z * di);
    o.w = f2b(v.w * di);
    ((ushort4*)xs)[i] = o;
}

// ---- pass 6: gather. One wave per row, lane d = feature d. 4-deep MLP unroll. ----
__global__ void gather_kernel(const unsigned short* __restrict__ xs, const float* __restrict__ dinv,
                              const int* __restrict__ rowptr, const int* __restrict__ sortedCol,
                              float* __restrict__ out) {
    int t = blockIdx.x * blockDim.x + threadIdx.x;
    int r = t >> 6;
    int d = t & 63;
    if (r >= N_NODES) return;
    int start = rowptr[r];
    int end = rowptr[r + 1];
    float dr = dinv[r];
    float acc = b2f(xs[r * D + d]);              // self-loop term (xs already has dr)
    for (int j = start; j < end; j += 64) {
        int idx = j + d;
        int cj = 0;
        if (idx < end) cj = sortedCol[idx];
        int n = min(64, end - j);
        int k = 0;
        for (; k + 4 <= n; k += 4) {
            int c0 = __shfl(cj, k);
            int c1 = __shfl(cj, k + 1);
            int c2 = __shfl(cj, k + 2);
            int c3 = __shfl(cj, k + 3);
            float v0 = b2f(xs[c0 * D + d]);      // 4 independent random 128B loads in flight
            float v1 = b2f(xs[c1 * D + d]);
            float v2 = b2f(xs[c2 * D + d]);
            float v3 = b2f(xs[c3 * D + d]);
            acc += (v0 + v1) + (v2 + v3);
        }
        for (; k < n; k++) {
            int c = __shfl(cj, k);
            acc += b2f(xs[c * D + d]);
        }
    }
    out[r * D + d] = dr * acc;
}

extern "C" void kernel_launch(void* const* d_in, const int* in_sizes, int n_in,
                              void* d_out, int out_size, void* d_ws, size_t ws_size,
                              hipStream_t stream) {
    const float* x = (const float*)d_in[0];
    const int* ei = (const int*)d_in[1];
    float* out = (float*)d_out;

    // workspace layout (~28 MB)
    int* offsets = (int*)d_ws;                        // [FLATN]
    int* blocksums = offsets + FLATN;                 // [1024]
    int* rowptr = blocksums + 1024;                   // [N_NODES+1]
    float* dinv = (float*)(rowptr + N_NODES + 1);     // [N_NODES]
    int* epack = (int*)(dinv + N_NODES);              // [N_EDGES]
    int* sortedCol = epack + N_EDGES;                 // [N_EDGES]
    unsigned short* xs = (unsigned short*)(sortedCol + N_EDGES); // [N_NODES*D]

    count_kernel<<<PBLK, 256, 0, stream>>>(ei, offsets);
    scan1_kernel<<<SB1, 256, 0, stream>>>(offsets, blocksums);
    scan2_kernel<<<1, 1024, 0, stream>>>(blocksums, rowptr);
    scatter_part_kernel<<<PBLK, 256, 0, stream>>>(ei, offsets, blocksums, epack);
    rowsort_kernel<<<NB, 256, 0, stream>>>(offsets, blocksums, rowptr, epack, rowptr, dinv, sortedCol);
    convert_kernel<<<(N_NODES * D / 4 + 255) / 256, 256, 0, stream>>>(x, dinv, xs);
    gather_kernel<<<(N_NODES * D + 255) / 256, 256, 0, stream>>>(xs, dinv, rowptr, sortedCol, out);
}